// Round 1
// baseline (309.314 us; speedup 1.0000x reference)
//
#include <hip/hip_runtime.h>
#include <stdint.h>

#define N_ANCH 25200
#define NCLS   80
#define KSEL   2048
#define MAXDET 1000
#define CONF_T 0.4f
#define IOU_T  0.45f
#define MAX_WH 7680.0f

// workspace byte offsets (total 819200 B)
#define WS_KEYS      0        // uint32 [25200]
#define WS_CLS       102400   // int32  [25200]
#define WS_SELSCORE  204800   // float  [2048]
#define WS_SELBOX    212992   // float4 [2048]  (class-offset boxes)
#define WS_DETCAND   245760   // float  [2048*6]
#define WS_MASK      294912   // uint32 [2048*64]

// ---------------------------------------------------------------- img kernel
// x[c][h][w] = img[h][w][2-c] / 255   (transpose(2,0,1) then channel reverse)
__global__ void img_kernel(const int* __restrict__ img, float* __restrict__ xout) {
    int i = blockIdx.x * 256 + threadIdx.x;
    if (i >= 640 * 640 * 3) return;
    int c   = i / 409600;            // 640*640
    int rem = i - c * 409600;        // h*640 + w
    int v = img[rem * 3 + (2 - c)];
    xout[i] = (float)v / 255.0f;     // division to match numpy rounding exactly
}

// -------------------------------------------------------------- score kernel
// per-anchor: conf = max_c(p[5+c]*p[4]); cls = argmax (first occurrence);
// score = conf > 0.4 ? conf : -1;  key = order-preserving uint map
__global__ void score_kernel(const float* __restrict__ pred0,
                             uint32_t* __restrict__ keys, int* __restrict__ cls) {
    int a = blockIdx.x * 256 + threadIdx.x;
    if (a >= N_ANCH) return;
    const float* p = pred0 + (size_t)a * 85;
    float obj = p[4];
    float best = -1e30f;
    int bc = 0;
    for (int c = 0; c < NCLS; ++c) {
        float v = p[5 + c] * obj;
        if (v > best) { best = v; bc = c; }   // strict > keeps first max (jnp.argmax)
    }
    float score = (best > CONF_T) ? best : -1.0f;
    uint32_t bits = __float_as_uint(score);
    uint32_t key = (bits & 0x80000000u) ? ~bits : (bits | 0x80000000u);
    keys[a] = key;
    cls[a] = bc;
}

// --------------------------------------------------------------- topk kernel
// Single block, 1024 threads. Finds exact 2048th-largest key via 32-step
// bitwise binary search, compacts >T and ==T into LDS, bitonic-sorts 4096
// packed (key desc, idx asc) items, emits sel arrays + boxes + det candidates.
__global__ void __launch_bounds__(1024)
topk_kernel(const uint32_t* __restrict__ keys, const float* __restrict__ pred0,
            const int* __restrict__ cls, float* __restrict__ sel_score,
            float4* __restrict__ selbox, float* __restrict__ det_cand) {
    __shared__ int s_cnt;
    __shared__ int s_gt, s_eq;
    __shared__ unsigned long long s_items[4096];
    int tid = threadIdx.x;
    int lane = tid & 63;

    // ---- binary search for T = max{t : count(keys >= t) >= KSEL}
    uint32_t T = 0;
    for (int bit = 31; bit >= 0; --bit) {
        uint32_t cand = T | (1u << bit);
        if (tid == 0) s_cnt = 0;
        __syncthreads();
        int c = 0;
        for (int i = tid; i < N_ANCH; i += 1024) c += (keys[i] >= cand) ? 1 : 0;
        for (int off = 32; off > 0; off >>= 1) c += __shfl_down(c, off, 64);
        if (lane == 0) atomicAdd(&s_cnt, c);
        __syncthreads();
        int total = s_cnt;
        if (total >= KSEL) T = cand;
        __syncthreads();
    }

    // ---- compact: keys > T  -> [0,2048) ;  keys == T -> [2048,4096)
    for (int i = tid; i < 4096; i += 1024) s_items[i] = 0ull;
    if (tid == 0) { s_gt = 0; s_eq = 0; }
    __syncthreads();
    for (int i = tid; i < N_ANCH; i += 1024) {
        uint32_t k = keys[i];
        if (k > T) {
            int p = atomicAdd(&s_gt, 1);
            if (p < 2048)
                s_items[p] = ((unsigned long long)k << 32) | (uint32_t)(~(uint32_t)i);
        } else if (k == T) {
            int p = atomicAdd(&s_eq, 1);
            if (p < 2048)
                s_items[2048 + p] = ((unsigned long long)k << 32) | (uint32_t)(~(uint32_t)i);
        }
    }
    __syncthreads();

    // ---- bitonic sort 4096 items, DESCENDING (key desc, ~idx desc = idx asc)
    for (unsigned k = 2; k <= 4096; k <<= 1) {
        for (unsigned j = k >> 1; j > 0; j >>= 1) {
            for (unsigned t = tid; t < 4096; t += 1024) {
                unsigned ixj = t ^ j;
                if (ixj > t) {
                    unsigned long long A = s_items[t], B = s_items[ixj];
                    bool up = ((t & k) == 0);         // descending blocks
                    if (up ? (A < B) : (A > B)) { s_items[t] = B; s_items[ixj] = A; }
                }
            }
            __syncthreads();
        }
    }

    // ---- emit top-2048: score, offset box, det candidate row
    for (int r = tid; r < KSEL; r += 1024) {
        unsigned long long it = s_items[r];
        uint32_t key = (uint32_t)(it >> 32);
        int a = (int)(~(uint32_t)it);
        uint32_t fb = (key & 0x80000000u) ? (key & 0x7FFFFFFFu) : ~key;
        float score = __uint_as_float(fb);
        const float* p = pred0 + (size_t)a * 85;
        float x = p[0], y = p[1], w = p[2], h = p[3];
        float x1 = x - w * 0.5f, y1 = y - h * 0.5f;
        float x2 = x + w * 0.5f, y2 = y + h * 0.5f;
        float cf = (float)cls[a];
        float off = cf * MAX_WH;
        selbox[r] = make_float4(x1 + off, y1 + off, x2 + off, y2 + off);
        float* dc = det_cand + (size_t)r * 6;
        dc[0] = x1; dc[1] = y1; dc[2] = x2; dc[3] = y2; dc[4] = score; dc[5] = cf;
        sel_score[r] = score;
    }
}

// --------------------------------------------------------------- mask kernel
// M[i][w] bit b set  <=>  j = w*32+b > i  &&  iou(box_i, box_j) > 0.45
__global__ void __launch_bounds__(256)
mask_kernel(const float4* __restrict__ selbox, uint32_t* __restrict__ M) {
    __shared__ float4 sb[KSEL];
    for (int i = threadIdx.x; i < KSEL; i += 256) sb[i] = selbox[i];
    __syncthreads();
    int t = blockIdx.x * 256 + threadIdx.x;   // t in [0, 2048*64)
    int row = t >> 6;
    int w = t & 63;
    float4 a = sb[row];
    float areaA = (a.z - a.x) * (a.w - a.y);
    uint32_t bits = 0;
    for (int b = 0; b < 32; ++b) {
        int j = w * 32 + b;
        if (j > row) {
            float4 q = sb[j];
            float lx = fmaxf(a.x, q.x), ly = fmaxf(a.y, q.y);
            float rx = fminf(a.z, q.z), ry = fminf(a.w, q.w);
            float ww = fmaxf(rx - lx, 0.0f), hh = fmaxf(ry - ly, 0.0f);
            float inter = ww * hh;
            float areaB = (q.z - q.x) * (q.w - q.y);
            float iou = inter / (areaA + areaB - inter + 1e-7f);
            if (iou > IOU_T) bits |= (1u << b);
        }
    }
    M[t] = bits;
}

// ---------------------------------------------------------------- nms kernel
// One wave (64 lanes). Lane l owns bits [32l, 32l+32) of the removed mask.
// Rows processed in chunks of 32; lane c resolves the serial dependency for
// its word locally and broadcasts kept-mask once per chunk (1 shfl / 32 rows).
__global__ void __launch_bounds__(64)
nms_kernel(const uint32_t* __restrict__ M, const float* __restrict__ sel_score,
           const float* __restrict__ det_cand, float* __restrict__ det) {
    int lane = threadIdx.x;
    uint32_t removed = 0;
    for (int b = 0; b < 32; ++b)
        if (!(sel_score[lane * 32 + b] > CONF_T)) removed |= (1u << b);

    for (int c = 0; c < 64; ++c) {
        uint32_t rw[32];
        #pragma unroll
        for (int b = 0; b < 32; ++b)
            rw[b] = M[(size_t)(c * 32 + b) * 64 + lane];
        uint32_t keptmask = 0;
        if (lane == c) {
            uint32_t myrem = removed;
            #pragma unroll
            for (int b = 0; b < 32; ++b) {
                if (!((myrem >> b) & 1u)) { keptmask |= (1u << b); myrem |= rw[b]; }
            }
        }
        keptmask = __shfl(keptmask, c, 64);
        #pragma unroll
        for (int b = 0; b < 32; ++b)
            if ((keptmask >> b) & 1u) removed |= rw[b];
    }

    // rank + emit first 1000 kept rows (already score-descending), zero-fill
    uint32_t kw = ~removed;
    int cnt = __popc(kw);
    int pre = cnt;
    for (int o = 1; o < 64; o <<= 1) {
        int n = __shfl_up(pre, o, 64);
        if (lane >= o) pre += n;
    }
    int excl = pre - cnt;
    int total = __shfl(pre, 63, 64);

    int r = excl;
    for (int b = 0; b < 32; ++b) {
        if ((kw >> b) & 1u) {
            if (r < MAXDET) {
                const float* src = det_cand + (size_t)(lane * 32 + b) * 6;
                float* dst = det + (size_t)r * 6;
                for (int j = 0; j < 6; ++j) dst[j] = src[j];
            }
            ++r;
        }
    }
    int start = total < MAXDET ? total : MAXDET;
    for (int z = start + lane; z < MAXDET; z += 64) {
        float* dst = det + (size_t)z * 6;
        for (int j = 0; j < 6; ++j) dst[j] = 0.0f;
    }
}

// ----------------------------------------------------------------- launcher
extern "C" void kernel_launch(void* const* d_in, const int* in_sizes, int n_in,
                              void* d_out, int out_size, void* d_ws, size_t ws_size,
                              hipStream_t stream) {
    const int*   img  = (const int*)d_in[0];
    const float* pred = (const float*)d_in[1];   // (8, 25200, 85); only batch 0 used
    float* out = (float*)d_out;                  // det[1000*6] then x[3*640*640]
    char* ws = (char*)d_ws;

    uint32_t* keys      = (uint32_t*)(ws + WS_KEYS);
    int*      cls       = (int*)(ws + WS_CLS);
    float*    sel_score = (float*)(ws + WS_SELSCORE);
    float4*   selbox    = (float4*)(ws + WS_SELBOX);
    float*    det_cand  = (float*)(ws + WS_DETCAND);
    uint32_t* M         = (uint32_t*)(ws + WS_MASK);

    img_kernel<<<(640 * 640 * 3 + 255) / 256, 256, 0, stream>>>(img, out + MAXDET * 6);
    score_kernel<<<(N_ANCH + 255) / 256, 256, 0, stream>>>(pred, keys, cls);
    topk_kernel<<<1, 1024, 0, stream>>>(keys, pred, cls, sel_score, selbox, det_cand);
    mask_kernel<<<(KSEL * 64) / 256, 256, 0, stream>>>(selbox, M);
    nms_kernel<<<1, 64, 0, stream>>>(M, sel_score, det_cand, out);
}

// Round 2
// 245.254 us; speedup vs baseline: 1.2612x; 1.2612x over previous
//
#include <hip/hip_runtime.h>
#include <stdint.h>

#define N_ANCH 25200
#define NCLS   80
#define KSEL   2048
#define MAXDET 1000
#define CONF_T 0.4f
#define IOU_T  0.45f
#define MAX_WH 7680.0f
#define HBINS  512
#define HBASE  0xBE00u

// workspace byte offsets (total 819200 B, same footprint as round 1)
#define WS_KEYS      0        // uint32 [25200]
#define WS_CLS       102400   // int32  [25200]
#define WS_SELSCORE  204800   // float  [2048]
#define WS_SELBOX    212992   // float4 [2048]  (class-offset boxes)
#define WS_DETCAND   245760   // float  [2048*6]
#define WS_MASK      294912   // uint32 [2048*64]
// ghist (512 u32 = 2 KB) aliases the first 2 KB of WS_MASK: it is consumed by
// topk_kernel BEFORE mask_kernel overwrites the region (stream-ordered).
#define WS_HIST      294912

// ---------------------------------------------------------------- img kernel
__global__ void img_kernel(const int* __restrict__ img, float* __restrict__ xout) {
    int i = blockIdx.x * 256 + threadIdx.x;
    if (i >= 640 * 640 * 3) return;
    int c   = i / 409600;
    int rem = i - c * 409600;
    int v = img[rem * 3 + (2 - c)];
    xout[i] = (float)v / 255.0f;
}

// -------------------------------------------------------------- score kernel
// per-anchor key + cls, plus a 512-bin global histogram of key>>16 - 0xBE00
__global__ void __launch_bounds__(256)
score_kernel(const float* __restrict__ pred0,
             uint32_t* __restrict__ keys, int* __restrict__ cls,
             uint32_t* __restrict__ ghist) {
    __shared__ uint32_t lh[HBINS];
    int tid = threadIdx.x;
    lh[tid] = 0; lh[tid + 256] = 0;
    __syncthreads();

    int a = blockIdx.x * 256 + tid;
    bool active = (a < N_ANCH);
    uint32_t key = 0;
    if (active) {
        const float* p = pred0 + (size_t)a * 85;
        float obj = p[4];
        float best = -1e30f;
        int bc = 0;
        for (int c = 0; c < NCLS; ++c) {
            float v = p[5 + c] * obj;
            if (v > best) { best = v; bc = c; }   // strict > = first-occurrence argmax
        }
        float score = (best > CONF_T) ? best : -1.0f;
        uint32_t bits = __float_as_uint(score);
        key = (bits & 0x80000000u) ? ~bits : (bits | 0x80000000u);
        keys[a] = key;
        cls[a] = bc;
        if (key >= (HBASE << 16))
            atomicAdd(&lh[(key >> 16) - HBASE], 1u);
    }
    __syncthreads();
    if (lh[tid])       atomicAdd(&ghist[tid],       lh[tid]);
    if (lh[tid + 256]) atomicAdd(&ghist[tid + 256], lh[tid + 256]);
}

// --------------------------------------------------------------- topk kernel
// Single block, 1024 threads. Suffix-scan of the 512-bin histogram gives the
// threshold bin B (count above = g < 2048, count through B >= 2048). One
// compaction pass collects all keys in bins >= B (~2.2K items) into LDS,
// bitonic sort 4096 desc by (key, ~idx), emit top-2048.
__global__ void __launch_bounds__(1024)
topk_kernel(const uint32_t* __restrict__ keys, const float* __restrict__ pred0,
            const int* __restrict__ cls, const uint32_t* __restrict__ ghist,
            float* __restrict__ sel_score, float4* __restrict__ selbox,
            float* __restrict__ det_cand) {
    __shared__ unsigned long long s_items[4096];
    __shared__ uint32_t s_suf[HBINS];
    __shared__ int s_B, s_g, s_n;
    int tid = threadIdx.x;

    if (tid < HBINS) s_suf[tid] = ghist[tid];
    if (tid == 0) { s_B = 0; s_g = 0; s_n = 0; }
    for (int i = tid; i < 4096; i += 1024) s_items[i] = 0ull;
    __syncthreads();

    // reverse (suffix) inclusive scan over 512 bins, Hillis-Steele
    for (int off = 1; off < HBINS; off <<= 1) {
        uint32_t v = 0;
        if (tid < HBINS)
            v = s_suf[tid] + ((tid + off < HBINS) ? s_suf[tid + off] : 0u);
        __syncthreads();
        if (tid < HBINS) s_suf[tid] = v;
        __syncthreads();
    }
    // B = max{b : suffix(b) >= K};  g = suffix(B+1)
    if (tid < HBINS) {
        uint32_t sb  = s_suf[tid];
        uint32_t sb1 = (tid < HBINS - 1) ? s_suf[tid + 1] : 0u;
        if (sb >= KSEL && sb1 < KSEL) { s_B = tid; s_g = (int)sb1; }
    }
    __syncthreads();
    uint32_t lim = (uint32_t)(HBASE + s_B) << 16;   // union = all keys >= lim

    // single compaction pass (order irrelevant — bitonic sorts)
    for (int i = tid; i < N_ANCH; i += 1024) {
        uint32_t k = keys[i];
        if (k >= lim) {
            int p = atomicAdd(&s_n, 1);
            if (p < 4096)
                s_items[p] = ((unsigned long long)k << 32) | (uint32_t)(~(uint32_t)i);
        }
    }
    __syncthreads();

    // bitonic sort 4096, DESCENDING (key desc, ~idx desc = idx asc)
    for (unsigned k = 2; k <= 4096; k <<= 1) {
        for (unsigned j = k >> 1; j > 0; j >>= 1) {
            for (unsigned t = tid; t < 4096; t += 1024) {
                unsigned ixj = t ^ j;
                if (ixj > t) {
                    unsigned long long A = s_items[t], B = s_items[ixj];
                    bool up = ((t & k) == 0);
                    if (up ? (A < B) : (A > B)) { s_items[t] = B; s_items[ixj] = A; }
                }
            }
            __syncthreads();
        }
    }

    // emit top-2048
    for (int r = tid; r < KSEL; r += 1024) {
        unsigned long long it = s_items[r];
        uint32_t key = (uint32_t)(it >> 32);
        int a = (int)(~(uint32_t)it);
        uint32_t fb = (key & 0x80000000u) ? (key & 0x7FFFFFFFu) : ~key;
        float score = __uint_as_float(fb);
        const float* p = pred0 + (size_t)a * 85;
        float x = p[0], y = p[1], w = p[2], h = p[3];
        float x1 = x - w * 0.5f, y1 = y - h * 0.5f;
        float x2 = x + w * 0.5f, y2 = y + h * 0.5f;
        float cf = (float)cls[a];
        float off = cf * MAX_WH;
        selbox[r] = make_float4(x1 + off, y1 + off, x2 + off, y2 + off);
        float* dc = det_cand + (size_t)r * 6;
        dc[0] = x1; dc[1] = y1; dc[2] = x2; dc[3] = y2; dc[4] = score; dc[5] = cf;
        sel_score[r] = score;
    }
}

// --------------------------------------------------------------- mask kernel
// SoA + skew (idx = j + j/32): lane reads j = lane*32+b -> bank (lane+b)%32,
// 2 lanes/bank = conflict-free (was 64-way on the float4 layout).
__global__ void __launch_bounds__(256)
mask_kernel(const float4* __restrict__ selbox, uint32_t* __restrict__ M) {
    __shared__ float sx1[KSEL + 64], sy1[KSEL + 64], sx2[KSEL + 64], sy2[KSEL + 64];
    for (int i = threadIdx.x; i < KSEL; i += 256) {
        float4 b = selbox[i];
        int ii = i + (i >> 5);
        sx1[ii] = b.x; sy1[ii] = b.y; sx2[ii] = b.z; sy2[ii] = b.w;
    }
    __syncthreads();
    int t = blockIdx.x * 256 + threadIdx.x;
    int row = t >> 6;
    int w = t & 63;
    int ri = row + (row >> 5);
    float ax1 = sx1[ri], ay1 = sy1[ri], ax2 = sx2[ri], ay2 = sy2[ri];
    float areaA = (ax2 - ax1) * (ay2 - ay1);
    uint32_t bits = 0;
    for (int b = 0; b < 32; ++b) {
        int j = w * 32 + b;
        if (j > row) {
            int jj = j + (j >> 5);
            float bx1 = sx1[jj], by1 = sy1[jj], bx2 = sx2[jj], by2 = sy2[jj];
            float lx = fmaxf(ax1, bx1), ly = fmaxf(ay1, by1);
            float rx = fminf(ax2, bx2), ry = fminf(ay2, by2);
            float ww = fmaxf(rx - lx, 0.0f), hh = fmaxf(ry - ly, 0.0f);
            float inter = ww * hh;
            float areaB = (bx2 - bx1) * (by2 - by1);
            float iou = inter / (areaA + areaB - inter + 1e-7f);
            if (iou > IOU_T) bits |= (1u << b);
        }
    }
    M[t] = bits;
}

// ---------------------------------------------------------------- nms kernel
__global__ void __launch_bounds__(64)
nms_kernel(const uint32_t* __restrict__ M, const float* __restrict__ sel_score,
           const float* __restrict__ det_cand, float* __restrict__ det) {
    int lane = threadIdx.x;
    uint32_t removed = 0;
    for (int b = 0; b < 32; ++b)
        if (!(sel_score[lane * 32 + b] > CONF_T)) removed |= (1u << b);

    for (int c = 0; c < 64; ++c) {
        uint32_t rw[32];
        #pragma unroll
        for (int b = 0; b < 32; ++b)
            rw[b] = M[(size_t)(c * 32 + b) * 64 + lane];
        uint32_t keptmask = 0;
        if (lane == c) {
            uint32_t myrem = removed;
            #pragma unroll
            for (int b = 0; b < 32; ++b) {
                if (!((myrem >> b) & 1u)) { keptmask |= (1u << b); myrem |= rw[b]; }
            }
        }
        keptmask = __shfl(keptmask, c, 64);
        #pragma unroll
        for (int b = 0; b < 32; ++b)
            if ((keptmask >> b) & 1u) removed |= rw[b];
    }

    uint32_t kw = ~removed;
    int cnt = __popc(kw);
    int pre = cnt;
    for (int o = 1; o < 64; o <<= 1) {
        int n = __shfl_up(pre, o, 64);
        if (lane >= o) pre += n;
    }
    int excl = pre - cnt;
    int total = __shfl(pre, 63, 64);

    int r = excl;
    for (int b = 0; b < 32; ++b) {
        if ((kw >> b) & 1u) {
            if (r < MAXDET) {
                const float* src = det_cand + (size_t)(lane * 32 + b) * 6;
                float* dst = det + (size_t)r * 6;
                for (int j = 0; j < 6; ++j) dst[j] = src[j];
            }
            ++r;
        }
    }
    int start = total < MAXDET ? total : MAXDET;
    for (int z = start + lane; z < MAXDET; z += 64) {
        float* dst = det + (size_t)z * 6;
        for (int j = 0; j < 6; ++j) dst[j] = 0.0f;
    }
}

// ----------------------------------------------------------------- launcher
extern "C" void kernel_launch(void* const* d_in, const int* in_sizes, int n_in,
                              void* d_out, int out_size, void* d_ws, size_t ws_size,
                              hipStream_t stream) {
    const int*   img  = (const int*)d_in[0];
    const float* pred = (const float*)d_in[1];   // (8, 25200, 85); only batch 0 used
    float* out = (float*)d_out;                  // det[1000*6] then x[3*640*640]
    char* ws = (char*)d_ws;

    uint32_t* keys      = (uint32_t*)(ws + WS_KEYS);
    int*      cls       = (int*)(ws + WS_CLS);
    float*    sel_score = (float*)(ws + WS_SELSCORE);
    float4*   selbox    = (float4*)(ws + WS_SELBOX);
    float*    det_cand  = (float*)(ws + WS_DETCAND);
    uint32_t* M         = (uint32_t*)(ws + WS_MASK);
    uint32_t* ghist     = (uint32_t*)(ws + WS_HIST);   // aliases M[0..512) — safe, see above

    hipMemsetAsync(ghist, 0, HBINS * sizeof(uint32_t), stream);
    img_kernel<<<(640 * 640 * 3 + 255) / 256, 256, 0, stream>>>(img, out + MAXDET * 6);
    score_kernel<<<(N_ANCH + 255) / 256, 256, 0, stream>>>(pred, keys, cls, ghist);
    topk_kernel<<<1, 1024, 0, stream>>>(keys, pred, cls, ghist, sel_score, selbox, det_cand);
    mask_kernel<<<(KSEL * 64) / 256, 256, 0, stream>>>(selbox, M);
    nms_kernel<<<1, 64, 0, stream>>>(M, sel_score, det_cand, out);
}